// Round 1
// baseline (460.905 us; speedup 1.0000x reference)
//
#include <hip/hip_runtime.h>

// HyenaSE gated causal depthwise conv, fp32.
// B=2, D=4096, L=4096, G=256, HL=128.
// out[b,d,t] = q[b,d,t] * sum_{j=0..127} h[d%G, j] * (k*x)[b,d, t-127+j]
//
// R2: rolling register window (2 LDS reads/chunk), filter via scalar cache,
//     q prefetched before the K-loop.
// R3: cross-row software pipeline. Each block owns ROWS=4 consecutive rows
//     with a double-buffered LDS row buffer: while computing row r, the
//     x,k global loads for row r+1 are in flight (issued before the
//     compute), written to the other buffer after the compute. This
//     breaks the stage-then-compute convoy (VALUBusy was 47% ~= pure
//     VALU time / dur; staging memory was fully serialized with compute).

#define HSE_B  2
#define HSE_D  4096
#define HSE_L  4096
#define HSE_G  256
#define HSE_HL 128

constexpr int TPB  = 256;            // threads per block (4 waves)
constexpr int VPT  = 16;             // outputs per thread: 256*16 = 4096 = L
constexpr int PAD  = 128;            // causal zero pad (>= HL-1, float4 aligned)
constexpr int BUFN = PAD + HSE_L;    // 4224 floats = 16896 B per buffer
constexpr int ROWS = 4;              // rows per block (pipelined)
constexpr int GRID = (HSE_B * HSE_D) / ROWS;  // 2048 blocks

// XOR swizzle: permutes bank-quads (bits 2..4) using bits 5..7.
// Preserves float4 alignment; makes the stride-16-float read pattern
// conflict-free. 512B-periodic, and BUFN*4 = 16896 B is a multiple of
// 512 B, so the swizzle is self-contained per buffer.
__device__ __forceinline__ int swiz(int i) {
    return i ^ (((i >> 5) & 7) << 2);
}

__global__ __launch_bounds__(TPB, 4) void hyena_se_kernel(
    const float* __restrict__ x, const float* __restrict__ k,
    const float* __restrict__ q, const float* __restrict__ h,
    float* __restrict__ out)
{
    __shared__ float skx[2 * BUFN];  // 33792 B -> 4 blocks/CU (16 waves)

    const int tid  = threadIdx.x;
    const int t0   = tid * VPT;
    const int row0 = blockIdx.x * ROWS;

    // --- zero causal pads of both buffers (stay zero for all rows) ---
    if (tid < PAD / 4) {
        float4 z = make_float4(0.f, 0.f, 0.f, 0.f);
        ((float4*)skx)[swiz(4 * tid) >> 2] = z;
        ((float4*)(skx + BUFN))[swiz(4 * tid) >> 2] = z;
    }

    // --- prologue: stage row0 into buffer 0 (only exposed staging) ---
    {
        const size_t row = (size_t)row0 * HSE_L;
        #pragma unroll
        for (int r = 0; r < HSE_L / (4 * TPB); ++r) {   // 4 iters
            int pos = 4 * (tid + TPB * r);
            float4 xv = *(const float4*)(x + row + pos);
            float4 kv = *(const float4*)(k + row + pos);
            ((float4*)skx)[swiz(PAD + pos) >> 2] =
                make_float4(xv.x * kv.x, xv.y * kv.y, xv.z * kv.z, xv.w * kv.w);
        }
    }
    __syncthreads();

    // NOTE: rr loop deliberately NOT unrolled — full unroll would 4x the
    // ~18 KB compute body and blow L1I.
    for (int rr = 0; rr < ROWS; ++rr) {
        const int cur = rr & 1;
        float* __restrict__ buf = skx + cur * BUFN;
        const size_t row = (size_t)(row0 + rr) * HSE_L;
        const int d = (row0 + rr) & (HSE_D - 1);
        const float* __restrict__ hrow = h + (size_t)(d & (HSE_G - 1)) * HSE_HL;

        // --- issue q loads for this row (consumed in epilogue) ---
        float4 qv[VPT / 4];
        #pragma unroll
        for (int m = 0; m < VPT / 4; ++m)
            qv[m] = *(const float4*)(q + row + t0 + 4 * m);

        // --- issue x,k loads for NEXT row; in flight across the compute ---
        float4 xn[4], kn[4];
        const bool more = (rr + 1 < ROWS);
        if (more) {
            const size_t nrow = row + HSE_L;
            #pragma unroll
            for (int r = 0; r < 4; ++r) {
                int pos = 4 * (tid + TPB * r);
                xn[r] = *(const float4*)(x + nrow + pos);
                kn[r] = *(const float4*)(k + nrow + pos);
            }
        }

        // --- compute this row from buf ---
        float acc[VPT];
        #pragma unroll
        for (int v = 0; v < VPT; ++v) acc[v] = 0.f;

        // Rolling window w[] over LDS indices [t0 + 8*jc, t0 + 8*jc + 24).
        float w[24];
        #pragma unroll
        for (int m = 0; m < 4; ++m) {
            float4 wv = ((const float4*)buf)[swiz(t0 + 4 * m) >> 2];
            w[4*m+0] = wv.x; w[4*m+1] = wv.y; w[4*m+2] = wv.z; w[4*m+3] = wv.w;
        }

        #pragma unroll
        for (int jc = 0; jc < HSE_HL / 8; ++jc) {
            // 8 new window floats (2 conflict-free b128 reads)
            #pragma unroll
            for (int m = 0; m < 2; ++m) {
                float4 wv = ((const float4*)buf)[swiz(t0 + 8 * jc + 16 + 4 * m) >> 2];
                w[16 + 4*m + 0] = wv.x; w[16 + 4*m + 1] = wv.y;
                w[16 + 4*m + 2] = wv.z; w[16 + 4*m + 3] = wv.w;
            }
            // 8 filter taps from scalar cache (wave-uniform address)
            float hf[8];
            #pragma unroll
            for (int u = 0; u < 8; ++u) hf[u] = hrow[8 * jc + u];

            #pragma unroll
            for (int v = 0; v < VPT; ++v) {
                #pragma unroll
                for (int u = 0; u < 8; ++u) {
                    acc[v] = fmaf(hf[u], w[1 + v + u], acc[v]);
                }
            }
            // slide window by 8 (register renaming after full unroll)
            #pragma unroll
            for (int p = 0; p < 16; ++p) w[p] = w[p + 8];
        }

        // --- epilogue: out = q * acc (fire-and-forget stores) ---
        #pragma unroll
        for (int m = 0; m < VPT / 4; ++m) {
            float4 o;
            o.x = qv[m].x * acc[4*m + 0];
            o.y = qv[m].y * acc[4*m + 1];
            o.z = qv[m].z * acc[4*m + 2];
            o.w = qv[m].w * acc[4*m + 3];
            *(float4*)(out + row + t0 + 4 * m) = o;
        }

        // --- stage next row into the other buffer (loads landed by now) ---
        if (more) {
            float* __restrict__ nbuf = skx + (cur ^ 1) * BUFN;
            #pragma unroll
            for (int r = 0; r < 4; ++r) {
                int pos = 4 * (tid + TPB * r);
                ((float4*)nbuf)[swiz(PAD + pos) >> 2] = make_float4(
                    xn[r].x * kn[r].x, xn[r].y * kn[r].y,
                    xn[r].z * kn[r].z, xn[r].w * kn[r].w);
            }
        }
        __syncthreads();
    }
}

extern "C" void kernel_launch(void* const* d_in, const int* in_sizes, int n_in,
                              void* d_out, int out_size, void* d_ws, size_t ws_size,
                              hipStream_t stream) {
    const float* x = (const float*)d_in[0];
    const float* k = (const float*)d_in[1];
    const float* q = (const float*)d_in[2];
    const float* h = (const float*)d_in[3];
    float* o = (float*)d_out;

    dim3 grid(GRID);
    dim3 block(TPB);
    hyena_se_kernel<<<grid, block, 0, stream>>>(x, k, q, h, o);
}

// Round 2
// 408.812 us; speedup vs baseline: 1.1274x; 1.1274x over previous
//
#include <hip/hip_runtime.h>

// HyenaSE gated causal depthwise conv, fp32.
// B=2, D=4096, L=4096, G=256, HL=128.
// out[b,d,t] = q[b,d,t] * sum_{j=0..127} h[d%G, j] * (k*x)[b,d, t-127+j]
//
// R2: rolling register window (2 LDS reads/chunk), filter via scalar cache,
//     q prefetched before the K-loop. (154 us/dispatch, VALUBusy 47%)
// R3 (FAILED): reg-held cross-row prefetch -> scratch spills (+228 MB HBM).
// R4: async cross-row pipeline via global_load_lds (zero reg footprint).
//     Per block: raw x,k LDS buffers (linear, required by global_load_lds)
//     + swizzled kx buffer. While computing row r from kx, row r+1's x,k
//     stream into raw via vmcnt-tracked async loads. RAW s_barrier (not
//     __syncthreads) so the compiler's vmcnt(0)-before-barrier drain
//     doesn't serialize the pipeline. Each wave reads/loads only its own
//     raw chunks -> no cross-wave hazard on raw; two barriers/row protect kx.

#define HSE_B  2
#define HSE_D  4096
#define HSE_L  4096
#define HSE_G  256
#define HSE_HL 128

constexpr int TPB  = 256;            // threads per block (4 waves)
constexpr int VPT  = 16;             // outputs per thread: 256*16 = 4096 = L
constexpr int PAD  = 128;            // causal zero pad (>= HL-1, float4 aligned)
constexpr int LDS_KX = PAD + HSE_L;  // 4224 floats
// LDS: 4224 + 4096 + 4096 floats = 49664 B -> 3 blocks/CU (12 waves/CU)
constexpr int GRID = 768;            // 3 blocks/CU * 256 CU: single generation
constexpr int BASE_ROWS = (HSE_B * HSE_D) / GRID;   // 10; 512 blocks get +1

// XOR swizzle: permutes bank-quads (bits 2..4) using bits 5..7.
// Preserves float4 alignment; makes the stride-16-float window reads
// conflict-free. Maps [0,PAD) to itself, so the pad region stays intact.
__device__ __forceinline__ int swiz(int i) {
    return i ^ (((i >> 5) & 7) << 2);
}

// Async global->LDS, 16B per lane, no VGPR round-trip. LDS dest is
// wave-uniform base + lane*16; our linear per-thread chunks match that.
__device__ __forceinline__ void gload16(const float* gp, float* lp) {
    __builtin_amdgcn_global_load_lds(
        (const __attribute__((address_space(1))) void*)gp,
        (__attribute__((address_space(3))) void*)lp,
        16, 0, 0);
}

__global__ __launch_bounds__(TPB, 3) void hyena_se_kernel(
    const float* __restrict__ x, const float* __restrict__ k,
    const float* __restrict__ q, const float* __restrict__ h,
    float* __restrict__ out)
{
    __shared__ __align__(16) float skx[LDS_KX];  // swizzled kx (this row)
    __shared__ __align__(16) float sx[HSE_L];    // raw x (next row, linear)
    __shared__ __align__(16) float sk[HSE_L];    // raw k (next row, linear)

    const int tid = threadIdx.x;
    const int t0  = tid * VPT;
    const int bid = blockIdx.x;

    // Balanced row split: 8192 rows over 768 blocks = 10 + (bid%3 != 2).
    // Blocks sharing a CU are bid = b, b+256, b+512 -> all three residues
    // mod 3 -> every CU gets exactly 11+11+10 = 32 rows. No tail.
    const int rem   = bid % 3;
    const int nrows = BASE_ROWS + (rem != 2 ? 1 : 0);
    const int row0  = BASE_ROWS * bid + 2 * (bid / 3) + (rem < 2 ? rem : 2);

    // --- zero causal pad of kx (written once; swiz keeps [0,PAD) closed) ---
    if (tid < PAD / 4)
        ((float4*)skx)[swiz(4 * tid) >> 2] = make_float4(0.f, 0.f, 0.f, 0.f);

    // --- prologue: async-stage first row's x,k (only exposed staging) ---
    {
        const size_t row = (size_t)row0 * HSE_L;
        #pragma unroll
        for (int r = 0; r < 4; ++r) {
            int pos = 4 * (tid + TPB * r);
            gload16(x + row + pos, sx + pos);
            gload16(k + row + pos, sk + pos);
        }
    }

    for (int rr = 0; rr < nrows; ++rr) {
        const size_t row = (size_t)(row0 + rr) * HSE_L;
        const int d = (row0 + rr) & (HSE_D - 1);
        const float* __restrict__ hrow = h + (size_t)(d & (HSE_G - 1)) * HSE_HL;

        // Raw x,k for this row landed (they are the oldest vm entries; this
        // also drains last row's 4 stores -- cheap vs the 4096-cyc compute).
        asm volatile("s_waitcnt vmcnt(0)" ::: "memory");

        // --- convert raw -> swizzled kx. Each thread touches only its own
        //     chunks (same decomposition as the loads) -> wave-local. ---
        #pragma unroll
        for (int r = 0; r < 4; ++r) {
            int pos = 4 * (tid + TPB * r);
            float4 xv = *(const float4*)(sx + pos);
            float4 kv = *(const float4*)(sk + pos);
            ((float4*)skx)[swiz(PAD + pos) >> 2] =
                make_float4(xv.x * kv.x, xv.y * kv.y, xv.z * kv.z, xv.w * kv.w);
        }
        // Raw reads retired before raw is refilled (same-wave ordering).
        asm volatile("s_waitcnt lgkmcnt(0)" ::: "memory");
        __builtin_amdgcn_sched_barrier(0);

        // --- issue next row's async loads; in flight across the compute ---
        if (rr + 1 < nrows) {
            const size_t nrow = row + HSE_L;
            #pragma unroll
            for (int r = 0; r < 4; ++r) {
                int pos = 4 * (tid + TPB * r);
                gload16(x + nrow + pos, sx + pos);
                gload16(k + nrow + pos, sk + pos);
            }
        }

        // --- q prefetch (consumed in epilogue; rides the same vm queue) ---
        float4 qv[VPT / 4];
        #pragma unroll
        for (int m = 0; m < VPT / 4; ++m)
            qv[m] = *(const float4*)(q + row + t0 + 4 * m);

        // kx writes visible to all waves; vmcnt NOT drained (raw s_barrier,
        // not __syncthreads -- the latter would wait vmcnt(0) and kill the
        // async overlap).
        __builtin_amdgcn_sched_barrier(0);
        __builtin_amdgcn_s_barrier();
        __builtin_amdgcn_sched_barrier(0);

        // --- compute this row from kx (unchanged R2 rolling window) ---
        float acc[VPT];
        #pragma unroll
        for (int v = 0; v < VPT; ++v) acc[v] = 0.f;

        float w[24];
        #pragma unroll
        for (int m = 0; m < 4; ++m) {
            float4 wv = ((const float4*)skx)[swiz(t0 + 4 * m) >> 2];
            w[4*m+0] = wv.x; w[4*m+1] = wv.y; w[4*m+2] = wv.z; w[4*m+3] = wv.w;
        }

        #pragma unroll
        for (int jc = 0; jc < HSE_HL / 8; ++jc) {
            #pragma unroll
            for (int m = 0; m < 2; ++m) {
                float4 wv = ((const float4*)skx)[swiz(t0 + 8 * jc + 16 + 4 * m) >> 2];
                w[16 + 4*m + 0] = wv.x; w[16 + 4*m + 1] = wv.y;
                w[16 + 4*m + 2] = wv.z; w[16 + 4*m + 3] = wv.w;
            }
            float hf[8];
            #pragma unroll
            for (int u = 0; u < 8; ++u) hf[u] = hrow[8 * jc + u];

            #pragma unroll
            for (int v = 0; v < VPT; ++v) {
                #pragma unroll
                for (int u = 0; u < 8; ++u) {
                    acc[v] = fmaf(hf[u], w[1 + v + u], acc[v]);
                }
            }
            #pragma unroll
            for (int p = 0; p < 16; ++p) w[p] = w[p + 8];
        }

        // --- epilogue: out = q * acc ---
        #pragma unroll
        for (int m = 0; m < VPT / 4; ++m) {
            float4 o;
            o.x = qv[m].x * acc[4*m + 0];
            o.y = qv[m].y * acc[4*m + 1];
            o.z = qv[m].z * acc[4*m + 2];
            o.w = qv[m].w * acc[4*m + 3];
            *(float4*)(out + row + t0 + 4 * m) = o;
        }

        // All waves done reading kx before next iteration overwrites it.
        asm volatile("s_waitcnt lgkmcnt(0)" ::: "memory");
        __builtin_amdgcn_sched_barrier(0);
        __builtin_amdgcn_s_barrier();
        __builtin_amdgcn_sched_barrier(0);
    }
}

extern "C" void kernel_launch(void* const* d_in, const int* in_sizes, int n_in,
                              void* d_out, int out_size, void* d_ws, size_t ws_size,
                              hipStream_t stream) {
    const float* x = (const float*)d_in[0];
    const float* k = (const float*)d_in[1];
    const float* q = (const float*)d_in[2];
    const float* h = (const float*)d_in[3];
    float* o = (float*)d_out;

    dim3 grid(GRID);
    dim3 block(TPB);
    hyena_se_kernel<<<grid, block, 0, stream>>>(x, k, q, h, o);
}